// Round 2
// baseline (3244.623 us; speedup 1.0000x reference)
//
#include <hip/hip_runtime.h>

// SNN 2-layer Leaky net, reset_mechanism='subtract'.
//  x[4096,784] f32, W1[2048,784], b1[2048], W2[10,2048], b2[10]
//  out: spk2_rec[25,4096,10] ++ mem2_rec[25,4096,10]  (f32)

#define D_IN   784
#define D_H    2048
#define D_OUT  10
#define NSTEPS 25
#define BETAF  0.95f
#define THRF   1.0f

// ---------------- Kernel 1: cur1 = x @ W1^T + b1  (f32, VALU) ----------------
#define BM 128
#define BN 128
#define BK 16

__global__ __launch_bounds__(256) void gemm_cur1(
    const float* __restrict__ A,    // x [M][784]
    const float* __restrict__ W,    // W1 [2048][784]
    const float* __restrict__ bias, // b1 [2048]
    float* __restrict__ C)          // cur1 [M][2048]
{
    __shared__ float As[BK][BM + 4];
    __shared__ float Bs[BK][BN + 4];
    const int bm = blockIdx.y * BM;
    const int bn = blockIdx.x * BN;
    const int tid = threadIdx.x;
    const int tx = tid & 15, ty = tid >> 4;

    float c[8][8];
#pragma unroll
    for (int i = 0; i < 8; ++i)
#pragma unroll
        for (int j = 0; j < 8; ++j) c[i][j] = 0.f;

    for (int kb = 0; kb < D_IN; kb += BK) {
        // stage 128x16 tiles of A and W (both row-major, K contiguous)
#pragma unroll
        for (int q = 0; q < 2; ++q) {
            int i   = tid * 2 + q;       // 0..511 float4 slots
            int row = i >> 2;            // 0..127
            int c4  = (i & 3) * 4;       // k offset 0,4,8,12
            float4 va = *reinterpret_cast<const float4*>(&A[(size_t)(bm + row) * D_IN + kb + c4]);
            As[c4 + 0][row] = va.x; As[c4 + 1][row] = va.y;
            As[c4 + 2][row] = va.z; As[c4 + 3][row] = va.w;
            float4 vb = *reinterpret_cast<const float4*>(&W[(size_t)(bn + row) * D_IN + kb + c4]);
            Bs[c4 + 0][row] = vb.x; Bs[c4 + 1][row] = vb.y;
            Bs[c4 + 2][row] = vb.z; Bs[c4 + 3][row] = vb.w;
        }
        __syncthreads();
#pragma unroll
        for (int k = 0; k < BK; ++k) {
            float a[8], b[8];
#pragma unroll
            for (int i = 0; i < 8; ++i) a[i] = As[k][ty * 8 + i];
#pragma unroll
            for (int j = 0; j < 8; ++j) b[j] = Bs[k][tx * 8 + j];
#pragma unroll
            for (int i = 0; i < 8; ++i)
#pragma unroll
                for (int j = 0; j < 8; ++j) c[i][j] = fmaf(a[i], b[j], c[i][j]);
        }
        __syncthreads();
    }
#pragma unroll
    for (int i = 0; i < 8; ++i) {
        const int gr = bm + ty * 8 + i;
#pragma unroll
        for (int j = 0; j < 8; ++j) {
            const int gc = bn + tx * 8 + j;
            C[(size_t)gr * D_H + gc] = c[i][j] + bias[gc];
        }
    }
}

// ------------- Kernel 2: fused 25-step recurrence, 2 rows per wave -------------
// Per-row state lives in registers for all 25 steps; W2 (80KB f32) in LDS.
__global__ __launch_bounds__(256, 2) void snn_steps(
    const float* __restrict__ cur1,   // [B][2048]
    const float* __restrict__ W2,     // [10][2048] row-major
    const float* __restrict__ b2,     // [10]
    float* __restrict__ out_spk,      // [25][B][10]
    float* __restrict__ out_mem,      // [25][B][10]
    int Btot)
{
    __shared__ float W2s[D_OUT * D_H];  // 80 KB
    const int tid = threadIdx.x;

    // cooperative W2 load (flat copy, float4, coalesced)
    for (int i = tid * 4; i < D_OUT * D_H; i += 256 * 4) {
        float4 v = *reinterpret_cast<const float4*>(&W2[i]);
        *reinterpret_cast<float4*>(&W2s[i]) = v;
    }
    float b2r[D_OUT];
#pragma unroll
    for (int o = 0; o < D_OUT; ++o) b2r[o] = b2[o];
    __syncthreads();

    const int lane = tid & 63;
    const int wv   = tid >> 6;
    const int row0 = blockIdx.x * 8 + wv * 2;   // 2 rows per wave

    const float* __restrict__ c0p = cur1 + (size_t)row0 * D_H;
    const float* __restrict__ c1p = c0p + D_H;

    // lane owns h = lane + 64*j  (j = 0..31): coalesced global, stride-1 LDS reads
    float cu[2][32], mm[2][32];
#pragma unroll
    for (int j = 0; j < 32; ++j) {
        cu[0][j] = c0p[lane + 64 * j];
        cu[1][j] = c1p[lane + 64 * j];
        mm[0][j] = 0.f; mm[1][j] = 0.f;
    }
    float m2[2][D_OUT];
#pragma unroll
    for (int o = 0; o < D_OUT; ++o) { m2[0][o] = 0.f; m2[1][o] = 0.f; }

#pragma unroll 1
    for (int t = 0; t < NSTEPS; ++t) {
        float acc0[D_OUT], acc1[D_OUT];
#pragma unroll
        for (int o = 0; o < D_OUT; ++o) { acc0[o] = 0.f; acc1[o] = 0.f; }

#pragma unroll
        for (int j = 0; j < 32; ++j) {
            // Leaky layer-1 update (reset from PREVIOUS mem, then decay+input, then fire)
            float r0 = mm[0][j] > THRF ? 1.f : 0.f;
            float v0 = fmaf(BETAF, mm[0][j], cu[0][j]) - r0;
            mm[0][j] = v0;
            float s0 = v0 > THRF ? 1.f : 0.f;

            float r1 = mm[1][j] > THRF ? 1.f : 0.f;
            float v1 = fmaf(BETAF, mm[1][j], cu[1][j]) - r1;
            mm[1][j] = v1;
            float s1 = v1 > THRF ? 1.f : 0.f;

            const float* wrow = &W2s[lane + 64 * j];
#pragma unroll
            for (int o = 0; o < D_OUT; ++o) {
                float w = wrow[o * D_H];
                acc0[o] = fmaf(s0, w, acc0[o]);
                acc1[o] = fmaf(s1, w, acc1[o]);
            }
        }

        // 64-lane butterfly reduce; all lanes end with the full sums
#pragma unroll
        for (int o = 0; o < D_OUT; ++o) {
            float a0 = acc0[o], a1 = acc1[o];
#pragma unroll
            for (int m = 1; m < 64; m <<= 1) {
                a0 += __shfl_xor(a0, m);
                a1 += __shfl_xor(a1, m);
            }
            acc0[o] = a0; acc1[o] = a1;
        }

        // Leaky layer-2 update (replicated across lanes; static indexing only)
        float sel_s0 = 0.f, sel_m0 = 0.f, sel_s1 = 0.f, sel_m1 = 0.f;
#pragma unroll
        for (int o = 0; o < D_OUT; ++o) {
            float r20 = m2[0][o] > THRF ? 1.f : 0.f;
            float n0  = fmaf(BETAF, m2[0][o], acc0[o] + b2r[o]) - r20;
            m2[0][o]  = n0;
            float sp0 = n0 > THRF ? 1.f : 0.f;

            float r21 = m2[1][o] > THRF ? 1.f : 0.f;
            float n1  = fmaf(BETAF, m2[1][o], acc1[o] + b2r[o]) - r21;
            m2[1][o]  = n1;
            float sp1 = n1 > THRF ? 1.f : 0.f;

            if (lane == o) { sel_s0 = sp0; sel_m0 = n0; sel_s1 = sp1; sel_m1 = n1; }
        }
        if (lane < D_OUT) {
            const size_t base = (size_t)t * Btot * D_OUT;
            out_spk[base + (size_t)(row0 + 0) * D_OUT + lane] = sel_s0;
            out_mem[base + (size_t)(row0 + 0) * D_OUT + lane] = sel_m0;
            out_spk[base + (size_t)(row0 + 1) * D_OUT + lane] = sel_s1;
            out_mem[base + (size_t)(row0 + 1) * D_OUT + lane] = sel_m1;
        }
    }
}

extern "C" void kernel_launch(void* const* d_in, const int* in_sizes, int n_in,
                              void* d_out, int out_size, void* d_ws, size_t ws_size,
                              hipStream_t stream) {
    const float* x  = (const float*)d_in[0];
    const float* W1 = (const float*)d_in[1];
    const float* b1 = (const float*)d_in[2];
    const float* W2 = (const float*)d_in[3];
    const float* b2 = (const float*)d_in[4];
    float* out = (float*)d_out;

    const int Btot = in_sizes[0] / D_IN;       // 4096
    float* cur1 = (float*)d_ws;                // Btot * D_H f32 = 33.5 MB

    dim3 gg(D_H / BN, Btot / BM);              // (16, 32)
    gemm_cur1<<<gg, dim3(256), 0, stream>>>(x, W1, b1, cur1);

    float* out_spk = out;
    float* out_mem = out + (size_t)NSTEPS * Btot * D_OUT;
    snn_steps<<<dim3(Btot / 8), dim3(256), 0, stream>>>(cur1, W2, b2, out_spk, out_mem, Btot);
}

// Round 3
// 939.117 us; speedup vs baseline: 3.4550x; 3.4550x over previous
//
#include <hip/hip_runtime.h>

// SNN 2-layer Leaky net, reset_mechanism='subtract'.
//  x[4096,784] f32, W1[2048,784], b1[2048], W2[10,2048], b2[10]
//  out: spk2_rec[25,4096,10] ++ mem2_rec[25,4096,10]  (f32)

#define D_IN   784
#define D_H    2048
#define D_OUT  10
#define NSTEPS 25
#define BETAF  0.95f
#define THRF   1.0f

// ---------------- Kernel 1: cur1 = x @ W1^T + b1  (f32, VALU) ----------------
#define BM 128
#define BN 128
#define BK 16

__global__ __launch_bounds__(256) void gemm_cur1(
    const float* __restrict__ A,    // x [M][784]
    const float* __restrict__ W,    // W1 [2048][784]
    const float* __restrict__ bias, // b1 [2048]
    float* __restrict__ C)          // cur1 [M][2048]
{
    __shared__ float As[BK][BM + 4];
    __shared__ float Bs[BK][BN + 4];
    const int bm = blockIdx.y * BM;
    const int bn = blockIdx.x * BN;
    const int tid = threadIdx.x;
    const int tx = tid & 15, ty = tid >> 4;

    float c[8][8];
#pragma unroll
    for (int i = 0; i < 8; ++i)
#pragma unroll
        for (int j = 0; j < 8; ++j) c[i][j] = 0.f;

    for (int kb = 0; kb < D_IN; kb += BK) {
#pragma unroll
        for (int q = 0; q < 2; ++q) {
            int i   = tid * 2 + q;       // 0..511 float4 slots
            int row = i >> 2;            // 0..127
            int c4  = (i & 3) * 4;       // k offset 0,4,8,12
            float4 va = *reinterpret_cast<const float4*>(&A[(size_t)(bm + row) * D_IN + kb + c4]);
            As[c4 + 0][row] = va.x; As[c4 + 1][row] = va.y;
            As[c4 + 2][row] = va.z; As[c4 + 3][row] = va.w;
            float4 vb = *reinterpret_cast<const float4*>(&W[(size_t)(bn + row) * D_IN + kb + c4]);
            Bs[c4 + 0][row] = vb.x; Bs[c4 + 1][row] = vb.y;
            Bs[c4 + 2][row] = vb.z; Bs[c4 + 3][row] = vb.w;
        }
        __syncthreads();
#pragma unroll
        for (int k = 0; k < BK; ++k) {
            float a[8], b[8];
#pragma unroll
            for (int i = 0; i < 8; ++i) a[i] = As[k][ty * 8 + i];
#pragma unroll
            for (int j = 0; j < 8; ++j) b[j] = Bs[k][tx * 8 + j];
#pragma unroll
            for (int i = 0; i < 8; ++i)
#pragma unroll
                for (int j = 0; j < 8; ++j) c[i][j] = fmaf(a[i], b[j], c[i][j]);
        }
        __syncthreads();
    }
#pragma unroll
    for (int i = 0; i < 8; ++i) {
        const int gr = bm + ty * 8 + i;
#pragma unroll
        for (int j = 0; j < 8; ++j) {
            const int gc = bn + tx * 8 + j;
            C[(size_t)gr * D_H + gc] = c[i][j] + bias[gc];
        }
    }
}

// ---------------- DPP wave-64 sum: result valid in lane 63 ----------------
template<int CTRL>
__device__ __forceinline__ float dpp_add_step(float x) {
    int y = __builtin_amdgcn_update_dpp(0, __float_as_int(x), CTRL, 0xf, 0xf, true);
    return x + __int_as_float(y);
}
__device__ __forceinline__ float wave_sum63(float x) {
    x = dpp_add_step<0x111>(x);  // row_shr:1
    x = dpp_add_step<0x112>(x);  // row_shr:2
    x = dpp_add_step<0x114>(x);  // row_shr:4
    x = dpp_add_step<0x118>(x);  // row_shr:8  -> lane15 of each 16-row has row sum
    x = dpp_add_step<0x142>(x);  // row_bcast:15 -> lane31 = sum(0..31), lane63 = sum(32..63)
    x = dpp_add_step<0x143>(x);  // row_bcast:31 -> lane63 = full sum
    return x;                    // ONLY lane 63 holds the full 64-lane sum
}

// ------------- Kernel 2: fused 25-step recurrence, 2 rows per wave -------------
// State (cu, mem1) register-resident for all 25 steps; W2 in LDS as float2
// o-pair planes, h-major: Wp[h][p] = (W2[2p][h], W2[2p+1][h]).
// amdgpu_waves_per_eu(2,2): LDS caps us at 2 waves/EU anyway; pin it so the
// allocator uses the full 256-VGPR budget instead of spilling at 128.
__global__ __launch_bounds__(256)
__attribute__((amdgpu_waves_per_eu(2, 2)))
void snn_steps(
    const float* __restrict__ cur1,   // [B][2048]
    const float* __restrict__ W2,     // [10][2048] row-major
    const float* __restrict__ b2,     // [10]
    float* __restrict__ out_spk,      // [25][B][10]
    float* __restrict__ out_mem,      // [25][B][10]
    int Btot)
{
    __shared__ float2 Wp[D_H][5];     // 80 KB, h-major: 5 o-pairs contiguous per h
    const int tid = threadIdx.x;

    // cooperative build of the o-pair interleaved layout
    for (int h = tid; h < D_H; h += 256) {
#pragma unroll
        for (int p = 0; p < 5; ++p) {
            Wp[h][p] = make_float2(W2[(size_t)(2 * p) * D_H + h],
                                   W2[(size_t)(2 * p + 1) * D_H + h]);
        }
    }
    float b2r[D_OUT];
#pragma unroll
    for (int o = 0; o < D_OUT; ++o) b2r[o] = b2[o];
    __syncthreads();

    const int lane = tid & 63;
    const int wv   = tid >> 6;
    const int row0 = blockIdx.x * 8 + wv * 2;   // 2 rows per wave

    const float* __restrict__ c0p = cur1 + (size_t)row0 * D_H;
    const float* __restrict__ c1p = c0p + D_H;

    // lane owns h = lane + 64*j  (j = 0..31): coalesced global, stride-40B LDS (2-way = free)
    float cu[2][32], mm[2][32];
#pragma unroll
    for (int j = 0; j < 32; ++j) {
        cu[0][j] = c0p[lane + 64 * j];
        cu[1][j] = c1p[lane + 64 * j];
        mm[0][j] = 0.f; mm[1][j] = 0.f;
    }
    float m2[2][D_OUT];
#pragma unroll
    for (int o = 0; o < D_OUT; ++o) { m2[0][o] = 0.f; m2[1][o] = 0.f; }

#pragma unroll 1
    for (int t = 0; t < NSTEPS; ++t) {
        float acc0[D_OUT], acc1[D_OUT];
#pragma unroll
        for (int o = 0; o < D_OUT; ++o) { acc0[o] = 0.f; acc1[o] = 0.f; }

#pragma unroll
        for (int j = 0; j < 32; ++j) {
            // Leaky layer-1 (reset from PREVIOUS mem, decay+input, fire)
            float r0 = mm[0][j] > THRF ? 1.f : 0.f;
            float v0 = fmaf(BETAF, mm[0][j], cu[0][j]) - r0;
            mm[0][j] = v0;
            float s0 = v0 > THRF ? 1.f : 0.f;

            float r1 = mm[1][j] > THRF ? 1.f : 0.f;
            float v1 = fmaf(BETAF, mm[1][j], cu[1][j]) - r1;
            mm[1][j] = v1;
            float s1 = v1 > THRF ? 1.f : 0.f;

            const float2* wrow = &Wp[lane + 64 * j][0];
#pragma unroll
            for (int p = 0; p < 5; ++p) {
                float2 w = wrow[p];   // ds_read_b64, immediate offset p*8
                acc0[2 * p + 0] = fmaf(s0, w.x, acc0[2 * p + 0]);
                acc0[2 * p + 1] = fmaf(s0, w.y, acc0[2 * p + 1]);
                acc1[2 * p + 0] = fmaf(s1, w.x, acc1[2 * p + 0]);
                acc1[2 * p + 1] = fmaf(s1, w.y, acc1[2 * p + 1]);
            }
        }

        // VALU-pipe DPP tree reduce; full sums valid in lane 63 only
#pragma unroll
        for (int o = 0; o < D_OUT; ++o) {
            acc0[o] = wave_sum63(acc0[o]);
            acc1[o] = wave_sum63(acc1[o]);
        }

        // Layer-2 Leaky + stores: lane 63 owns both rows' 10 outputs
        if (lane == 63) {
            const size_t base = (size_t)t * Btot * D_OUT;
            float* sp0 = &out_spk[base + (size_t)(row0 + 0) * D_OUT];
            float* mp0 = &out_mem[base + (size_t)(row0 + 0) * D_OUT];
            float* sp1 = &out_spk[base + (size_t)(row0 + 1) * D_OUT];
            float* mp1 = &out_mem[base + (size_t)(row0 + 1) * D_OUT];
#pragma unroll
            for (int o = 0; o < D_OUT; ++o) {
                float r20 = m2[0][o] > THRF ? 1.f : 0.f;
                float n0  = fmaf(BETAF, m2[0][o], acc0[o] + b2r[o]) - r20;
                m2[0][o]  = n0;
                sp0[o] = n0 > THRF ? 1.f : 0.f;
                mp0[o] = n0;

                float r21 = m2[1][o] > THRF ? 1.f : 0.f;
                float n1  = fmaf(BETAF, m2[1][o], acc1[o] + b2r[o]) - r21;
                m2[1][o]  = n1;
                sp1[o] = n1 > THRF ? 1.f : 0.f;
                mp1[o] = n1;
            }
        }
    }
}

extern "C" void kernel_launch(void* const* d_in, const int* in_sizes, int n_in,
                              void* d_out, int out_size, void* d_ws, size_t ws_size,
                              hipStream_t stream) {
    const float* x  = (const float*)d_in[0];
    const float* W1 = (const float*)d_in[1];
    const float* b1 = (const float*)d_in[2];
    const float* W2 = (const float*)d_in[3];
    const float* b2 = (const float*)d_in[4];
    float* out = (float*)d_out;

    const int Btot = in_sizes[0] / D_IN;       // 4096
    float* cur1 = (float*)d_ws;                // Btot * D_H f32 = 33.5 MB

    dim3 gg(D_H / BN, Btot / BM);              // (16, 32)
    gemm_cur1<<<gg, dim3(256), 0, stream>>>(x, W1, b1, cur1);

    float* out_spk = out;
    float* out_mem = out + (size_t)NSTEPS * Btot * D_OUT;
    snn_steps<<<dim3(Btot / 8), dim3(256), 0, stream>>>(cur1, W2, b2, out_spk, out_mem, Btot);
}

// Round 7
// 508.175 us; speedup vs baseline: 6.3849x; 1.8480x over previous
//
#include <hip/hip_runtime.h>

// SNN 2-layer Leaky net, reset_mechanism='subtract'.
//  x[4096,784] f32, W1[2048,784], b1[2048], W2[10,2048], b2[10]
//  out: spk2_rec[25,4096,10] ++ mem2_rec[25,4096,10]  (f32)

#define D_IN   784
#define D_H    2048
#define D_OUT  10
#define NSTEPS 25
#define BETAF  0.95f
#define THRF   1.0f

// ---------------- Kernel 1: cur1 = x @ W1^T + b1  (f32, VALU) ----------------
#define BM 128
#define BN 128
#define BK 16

__global__ __launch_bounds__(256) void gemm_cur1(
    const float* __restrict__ A,    // x [M][784]
    const float* __restrict__ W,    // W1 [2048][784]
    const float* __restrict__ bias, // b1 [2048]
    float* __restrict__ C)          // cur1 [M][2048]
{
    __shared__ float As[BK][BM + 4];
    __shared__ float Bs[BK][BN + 4];
    const int bm = blockIdx.y * BM;
    const int bn = blockIdx.x * BN;
    const int tid = threadIdx.x;
    const int tx = tid & 15, ty = tid >> 4;

    float c[8][8];
#pragma unroll
    for (int i = 0; i < 8; ++i)
#pragma unroll
        for (int j = 0; j < 8; ++j) c[i][j] = 0.f;

    for (int kb = 0; kb < D_IN; kb += BK) {
#pragma unroll
        for (int q = 0; q < 2; ++q) {
            int i   = tid * 2 + q;       // 0..511 float4 slots
            int row = i >> 2;            // 0..127
            int c4  = (i & 3) * 4;       // k offset 0,4,8,12
            float4 va = *reinterpret_cast<const float4*>(&A[(size_t)(bm + row) * D_IN + kb + c4]);
            As[c4 + 0][row] = va.x; As[c4 + 1][row] = va.y;
            As[c4 + 2][row] = va.z; As[c4 + 3][row] = va.w;
            float4 vb = *reinterpret_cast<const float4*>(&W[(size_t)(bn + row) * D_IN + kb + c4]);
            Bs[c4 + 0][row] = vb.x; Bs[c4 + 1][row] = vb.y;
            Bs[c4 + 2][row] = vb.z; Bs[c4 + 3][row] = vb.w;
        }
        __syncthreads();
#pragma unroll
        for (int k = 0; k < BK; ++k) {
            float a[8], b[8];
#pragma unroll
            for (int i = 0; i < 8; ++i) a[i] = As[k][ty * 8 + i];
#pragma unroll
            for (int j = 0; j < 8; ++j) b[j] = Bs[k][tx * 8 + j];
#pragma unroll
            for (int i = 0; i < 8; ++i)
#pragma unroll
                for (int j = 0; j < 8; ++j) c[i][j] = fmaf(a[i], b[j], c[i][j]);
        }
        __syncthreads();
    }
#pragma unroll
    for (int i = 0; i < 8; ++i) {
        const int gr = bm + ty * 8 + i;
#pragma unroll
        for (int j = 0; j < 8; ++j) {
            const int gc = bn + tx * 8 + j;
            C[(size_t)gr * D_H + gc] = c[i][j] + bias[gc];
        }
    }
}

// ---------------- DPP wave-64 sum: result valid in lane 63 ----------------
template<int CTRL>
__device__ __forceinline__ float dpp_add_step(float x) {
    int y = __builtin_amdgcn_update_dpp(0, __float_as_int(x), CTRL, 0xf, 0xf, true);
    return x + __int_as_float(y);
}
__device__ __forceinline__ float wave_sum63(float x) {
    x = dpp_add_step<0x111>(x);  // row_shr:1
    x = dpp_add_step<0x112>(x);  // row_shr:2
    x = dpp_add_step<0x114>(x);  // row_shr:4
    x = dpp_add_step<0x118>(x);  // row_shr:8  -> lane15 of each 16-row has row sum
    x = dpp_add_step<0x142>(x);  // row_bcast:15 -> lane31 = sum(0..31), lane63 = sum(32..63)
    x = dpp_add_step<0x143>(x);  // row_bcast:31 -> lane63 = full sum
    return x;                    // ONLY lane 63 holds the full 64-lane sum
}

// ------------- Kernel 2: fused 25-step recurrence, 2 rows per wave -------------
// Register state is ONLY mem1 (mm[2][32]) + acc + m2 (~110 regs): cur1 is
// re-loaded from global every step (it's read-only, L2/L3-resident, and the
// per-step asm memory clobber stops the compiler CSE-ing the 25 load sets
// into pre-loop registers — that was the round-2/3 spill source).
// W2 in LDS as float2 o-pair planes, h-major: Wp[h][p]=(W2[2p][h],W2[2p+1][h]).
__global__ __launch_bounds__(256)
__attribute__((amdgpu_waves_per_eu(2, 2)))
void snn_steps(
    const float* __restrict__ cur1,   // [B][2048]
    const float* __restrict__ W2,     // [10][2048] row-major
    const float* __restrict__ b2,     // [10]
    float* __restrict__ out_spk,      // [25][B][10]
    float* __restrict__ out_mem,      // [25][B][10]
    int Btot)
{
    __shared__ float2 Wp[D_H][5];     // 80 KB exactly (2 blocks/CU)
    const int tid = threadIdx.x;

    for (int h = tid; h < D_H; h += 256) {
#pragma unroll
        for (int p = 0; p < 5; ++p) {
            Wp[h][p] = make_float2(W2[(size_t)(2 * p) * D_H + h],
                                   W2[(size_t)(2 * p + 1) * D_H + h]);
        }
    }
    // wave-uniform -> SGPRs, no VGPR cost
    float b2r[D_OUT];
#pragma unroll
    for (int o = 0; o < D_OUT; ++o) b2r[o] = b2[o];
    __syncthreads();

    const int lane = tid & 63;
    const int wv   = tid >> 6;
    const int row0 = blockIdx.x * 8 + wv * 2;   // 2 rows per wave

    const float* __restrict__ c0p = cur1 + (size_t)row0 * D_H + lane;
    const float* __restrict__ c1p = c0p + D_H;

    // lane owns h = lane + 64*j (j=0..31); only mem1 is persistent state
    float mm[2][32];
#pragma unroll
    for (int j = 0; j < 32; ++j) { mm[0][j] = 0.f; mm[1][j] = 0.f; }
    float m2[2][D_OUT];
#pragma unroll
    for (int o = 0; o < D_OUT; ++o) { m2[0][o] = 0.f; m2[1][o] = 0.f; }

#pragma unroll 1
    for (int t = 0; t < NSTEPS; ++t) {
        // stop cross-iteration CSE/hoisting of the cur1 reloads
        asm volatile("" ::: "memory");

        float acc0[D_OUT], acc1[D_OUT];
#pragma unroll
        for (int o = 0; o < D_OUT; ++o) { acc0[o] = 0.f; acc1[o] = 0.f; }

#pragma unroll
        for (int j = 0; j < 32; ++j) {
            float cu0 = c0p[64 * j];   // L2/L3-hit reload, coalesced
            float cu1 = c1p[64 * j];

            // Leaky layer-1 (reset from PREVIOUS mem, decay+input, fire)
            float r0 = mm[0][j] > THRF ? 1.f : 0.f;
            float v0 = fmaf(BETAF, mm[0][j], cu0) - r0;
            mm[0][j] = v0;
            float s0 = v0 > THRF ? 1.f : 0.f;

            float r1 = mm[1][j] > THRF ? 1.f : 0.f;
            float v1 = fmaf(BETAF, mm[1][j], cu1) - r1;
            mm[1][j] = v1;
            float s1 = v1 > THRF ? 1.f : 0.f;

            const float2* wrow = &Wp[lane + 64 * j][0];
#pragma unroll
            for (int p = 0; p < 5; ++p) {
                float2 w = wrow[p];   // ds_read_b64, immediate offset p*8
                acc0[2 * p + 0] = fmaf(s0, w.x, acc0[2 * p + 0]);
                acc0[2 * p + 1] = fmaf(s0, w.y, acc0[2 * p + 1]);
                acc1[2 * p + 0] = fmaf(s1, w.x, acc1[2 * p + 0]);
                acc1[2 * p + 1] = fmaf(s1, w.y, acc1[2 * p + 1]);
            }
        }

        // VALU-pipe DPP tree reduce; full sums valid in lane 63 only
#pragma unroll
        for (int o = 0; o < D_OUT; ++o) {
            acc0[o] = wave_sum63(acc0[o]);
            acc1[o] = wave_sum63(acc1[o]);
        }

        // Layer-2 Leaky + stores: lane 63 owns both rows' 10 outputs
        if (lane == 63) {
            const size_t base = (size_t)t * Btot * D_OUT;
            float* sp0 = &out_spk[base + (size_t)(row0 + 0) * D_OUT];
            float* mp0 = &out_mem[base + (size_t)(row0 + 0) * D_OUT];
            float* sp1 = &out_spk[base + (size_t)(row0 + 1) * D_OUT];
            float* mp1 = &out_mem[base + (size_t)(row0 + 1) * D_OUT];
#pragma unroll
            for (int o = 0; o < D_OUT; ++o) {
                float r20 = m2[0][o] > THRF ? 1.f : 0.f;
                float n0  = fmaf(BETAF, m2[0][o], acc0[o] + b2r[o]) - r20;
                m2[0][o]  = n0;
                sp0[o] = n0 > THRF ? 1.f : 0.f;
                mp0[o] = n0;

                float r21 = m2[1][o] > THRF ? 1.f : 0.f;
                float n1  = fmaf(BETAF, m2[1][o], acc1[o] + b2r[o]) - r21;
                m2[1][o]  = n1;
                sp1[o] = n1 > THRF ? 1.f : 0.f;
                mp1[o] = n1;
            }
        }
    }
}

extern "C" void kernel_launch(void* const* d_in, const int* in_sizes, int n_in,
                              void* d_out, int out_size, void* d_ws, size_t ws_size,
                              hipStream_t stream) {
    const float* x  = (const float*)d_in[0];
    const float* W1 = (const float*)d_in[1];
    const float* b1 = (const float*)d_in[2];
    const float* W2 = (const float*)d_in[3];
    const float* b2 = (const float*)d_in[4];
    float* out = (float*)d_out;

    const int Btot = in_sizes[0] / D_IN;       // 4096
    float* cur1 = (float*)d_ws;                // Btot * D_H f32 = 33.5 MB

    dim3 gg(D_H / BN, Btot / BM);              // (16, 32)
    gemm_cur1<<<gg, dim3(256), 0, stream>>>(x, W1, b1, cur1);

    float* out_spk = out;
    float* out_mem = out + (size_t)NSTEPS * Btot * D_OUT;
    snn_steps<<<dim3(Btot / 8), dim3(256), 0, stream>>>(cur1, W2, b2, out_spk, out_mem, Btot);
}